// Round 3
// baseline (1087.580 us; speedup 1.0000x reference)
//
#include <hip/hip_runtime.h>
#include <math.h>

#define DIM 128
#define CAP 8192          // slots per bucket (mean fill 4096, sd 64 -> never overflows)
#define BSHIFT 8          // 256 nodes per bucket

// ---------------------------------------------------------------- utilities
__global__ void k_zero_int(int* __restrict__ p, int n) {
    int i = blockIdx.x * blockDim.x + threadIdx.x;
    if (i < n) p[i] = 0;
}

// Pass A: partition edges into buckets by dst>>8. Appends are sequential per
// bucket => full cache-line write utilization (vs 64B/4B scatter of old k_fill).
// Packed value: src (17 bits) | (dst & 255) << 17  (25 bits total).
__global__ __launch_bounds__(256) void k_bucket(const int* __restrict__ src,
                                                const int* __restrict__ dst,
                                                int* __restrict__ bcur,
                                                unsigned int* __restrict__ tmpe,
                                                int E) {
    int e0 = (blockIdx.x * 256 + threadIdx.x) * 4;
#pragma unroll
    for (int k = 0; k < 4; ++k) {
        int e = e0 + k;
        if (e < E) {
            int s = src[e];
            int d = dst[e];
            int b = d >> BSHIFT;
            int p = atomicAdd(&bcur[b], 1);
            if (p < CAP) tmpe[(size_t)b * CAP + p] = (unsigned int)s | ((unsigned int)(d & 255) << 17);
        }
    }
}

// Pass B: one workgroup per bucket. Stage bucket edges in LDS, LDS-histogram
// the 256 local nodes (-> cnt), LDS-scan (-> rs), then scatter src ids back
// into the SAME global region grouped by node. Scatter target is one 16-32KB
// region => L2-hot, dense lines on eviction. Replaces k_hist + 3 scan kernels.
__global__ __launch_bounds__(256) void k_scatter(unsigned int* __restrict__ tmpe,
                                                 const int* __restrict__ bcur,
                                                 int* __restrict__ rs,
                                                 int* __restrict__ cnt,
                                                 int N) {
    __shared__ unsigned int se[CAP];   // 32 KB
    __shared__ int hist[256];
    __shared__ int sh[256];
    __shared__ int cur[256];
    int b = blockIdx.x;
    int t = threadIdx.x;
    size_t base = (size_t)b * CAP;
    int m = bcur[b];
    if (m > CAP) m = CAP;
    for (int i = t; i < m; i += 256) se[i] = tmpe[base + i];
    hist[t] = 0;
    __syncthreads();
    for (int i = t; i < m; i += 256) atomicAdd(&hist[se[i] >> 17], 1);
    __syncthreads();
    // exclusive scan of hist over 256 entries
    int v = hist[t];
    sh[t] = v;
    __syncthreads();
    int run = v;
    for (int off = 1; off < 256; off <<= 1) {
        int y = (t >= off) ? sh[t - off] : 0;
        __syncthreads();
        run += y;
        sh[t] = run;
        __syncthreads();
    }
    int excl = run - v;
    int node = (b << BSHIFT) + t;
    if (node < N) {
        rs[node] = (int)base + excl;
        cnt[node] = v;
    }
    cur[t] = excl;
    __syncthreads();
    // scatter: group src ids by local node, in place over the bucket region
    for (int i = t; i < m; i += 256) {
        unsigned int pk = se[i];
        int d = pk >> 17;
        int p = atomicAdd(&cur[d], 1);
        tmpe[base + p] = pk & 0x1FFFFu;
    }
}

// mean-aggregate: one wave per dst node. Each HALF-wave (32 lanes x float4 =
// 512B) covers a full 128-col row; halves take alternating edges; manual
// unroll-2 per half => 4 independent row-loads in flight per wave.
__global__ __launch_bounds__(256) void k_agg(const float* __restrict__ in,
                                             const int* __restrict__ rs,
                                             const int* __restrict__ cnt,
                                             const unsigned int* __restrict__ esrc,
                                             float* __restrict__ msg, int N) {
    int w = threadIdx.x >> 6;            // wave within block
    int half = (threadIdx.x >> 5) & 1;   // half-wave id
    int l32 = threadIdx.x & 31;          // lane within half
    int node = blockIdx.x * 4 + w;
    if (node >= N) return;
    int beg = rs[node];
    int deg = cnt[node];
    int end = beg + deg;
    int c = l32 * 4;
    float ax = 0.f, ay = 0.f, az = 0.f, aw = 0.f;
    int e = beg + half;                  // this half's first edge (stride 2)
    for (; e + 2 < end; e += 4) {        // unroll 2: edges e and e+2
        int s0 = esrc[e];
        int s1 = esrc[e + 2];
        float4 u = *(const float4*)(in + (size_t)s0 * DIM + c);
        float4 v = *(const float4*)(in + (size_t)s1 * DIM + c);
        ax += u.x + v.x;
        ay += u.y + v.y;
        az += u.z + v.z;
        aw += u.w + v.w;
    }
    if (e < end) {                       // at most one leftover per half
        int s0 = esrc[e];
        float4 u = *(const float4*)(in + (size_t)s0 * DIM + c);
        ax += u.x;
        ay += u.y;
        az += u.z;
        aw += u.w;
    }
    ax += __shfl_xor(ax, 32);
    ay += __shfl_xor(ay, 32);
    az += __shfl_xor(az, 32);
    aw += __shfl_xor(aw, 32);
    if (half == 0) {
        float invd = 1.0f / fmaxf((float)deg, 1.0f);
        float4 o;
        o.x = ax * invd;
        o.y = ay * invd;
        o.z = az * invd;
        o.w = aw * invd;
        *(float4*)(msg + (size_t)node * DIM + c) = o;
    }
}

// fused dual GEMM: out[m] = A[m] @ Ws^T + Hn[m] @ Wn^T + bias
// block: 256 threads, tile 64 rows x 128 cols (FULL rows), K chunks of 32.
// FUSE_NORM: L2-normalize rows in the epilogue (row spans 32 contiguous lanes).
template <bool FUSE_NORM>
__global__ __launch_bounds__(256) void k_gemm(const float* __restrict__ A,
                                              const float* __restrict__ Hn,
                                              const float* __restrict__ Ws,
                                              const float* __restrict__ Wn,
                                              const float* __restrict__ bias,
                                              float* __restrict__ out, int N) {
    __shared__ float As[32][68];   // k-major, padded
    __shared__ float Bs[32][132];  // k-major, padded
    int tid = threadIdx.x;
    int tr = tid >> 5;  // 0..7  -> row group (8 rows each)
    int tc = tid & 31;  // 0..31 -> col group (4 cols each)
    int m0 = blockIdx.x * 64;

    float acc[8][4];
#pragma unroll
    for (int i = 0; i < 8; ++i)
#pragma unroll
        for (int j = 0; j < 4; ++j) acc[i][j] = 0.f;

    for (int kb = 0; kb < 256; kb += 32) {
        const float* srcA = (kb < 128) ? A : Hn;
        const float* srcB = (kb < 128) ? Ws : Wn;
        int ka = kb & 127;
#pragma unroll
        for (int i = 0; i < 2; ++i) {
            int fi = tid + i * 256;
            int row = fi >> 3, kq = fi & 7;
            int m = m0 + row;
            float4 v = make_float4(0.f, 0.f, 0.f, 0.f);
            if (m < N) v = *(const float4*)(srcA + (size_t)m * DIM + ka + kq * 4);
            As[kq * 4 + 0][row] = v.x;
            As[kq * 4 + 1][row] = v.y;
            As[kq * 4 + 2][row] = v.z;
            As[kq * 4 + 3][row] = v.w;
        }
#pragma unroll
        for (int i = 0; i < 4; ++i) {
            int fi = tid + i * 256;
            int o = fi >> 3, kq = fi & 7;
            float4 v = *(const float4*)(srcB + o * DIM + ka + kq * 4);
            Bs[kq * 4 + 0][o] = v.x;
            Bs[kq * 4 + 1][o] = v.y;
            Bs[kq * 4 + 2][o] = v.z;
            Bs[kq * 4 + 3][o] = v.w;
        }
        __syncthreads();
#pragma unroll
        for (int kk = 0; kk < 32; ++kk) {
            float4 a0 = *(const float4*)&As[kk][tr * 8];
            float4 a1 = *(const float4*)&As[kk][tr * 8 + 4];
            float4 bv = *(const float4*)&Bs[kk][tc * 4];
            float av[8] = {a0.x, a0.y, a0.z, a0.w, a1.x, a1.y, a1.z, a1.w};
            float bw[4] = {bv.x, bv.y, bv.z, bv.w};
#pragma unroll
            for (int i = 0; i < 8; ++i)
#pragma unroll
                for (int j = 0; j < 4; ++j) acc[i][j] += av[i] * bw[j];
        }
        __syncthreads();
    }
    float4 bb = *(const float4*)(bias + tc * 4);
#pragma unroll
    for (int i = 0; i < 8; ++i) {
        int m = m0 + tr * 8 + i;
        if (m < N) {
            float4 o;
            o.x = acc[i][0] + bb.x;
            o.y = acc[i][1] + bb.y;
            o.z = acc[i][2] + bb.z;
            o.w = acc[i][3] + bb.w;
            if (FUSE_NORM) {
                // row m spans the 32 lanes sharing tr (contiguous lanes, one
                // 32-half of the wave): shfl_xor 16..1 reduces the full row.
                float ss = o.x * o.x + o.y * o.y + o.z * o.z + o.w * o.w;
                ss += __shfl_xor(ss, 16);
                ss += __shfl_xor(ss, 8);
                ss += __shfl_xor(ss, 4);
                ss += __shfl_xor(ss, 2);
                ss += __shfl_xor(ss, 1);
                float scale = 1.0f / fmaxf(sqrtf(ss), 1e-12f);
                o.x *= scale;
                o.y *= scale;
                o.z *= scale;
                o.w *= scale;
            }
            *(float4*)(out + (size_t)m * DIM + tc * 4) = o;
        }
    }
}

extern "C" void kernel_launch(void* const* d_in, const int* in_sizes, int n_in,
                              void* d_out, int out_size, void* d_ws, size_t ws_size,
                              hipStream_t stream) {
    const float* x   = (const float*)d_in[0];
    const int*   src = (const int*)d_in[1];
    const int*   dst = (const int*)d_in[2];
    const float* Ws1 = (const float*)d_in[3];
    const float* Wn1 = (const float*)d_in[4];
    const float* b1  = (const float*)d_in[5];
    const float* Ws2 = (const float*)d_in[6];
    const float* Wn2 = (const float*)d_in[7];
    const float* b2  = (const float*)d_in[8];
    float* out = (float*)d_out;

    int N = in_sizes[0] / DIM;
    int E = in_sizes[1];
    int NB = (N + (1 << BSHIFT) - 1) >> BSHIFT;

    // workspace carve-up (256B aligned)
    char* p = (char*)d_ws;
    size_t off = 0;
    auto carve = [&](size_t bytes) {
        void* r = p + off;
        off = (off + bytes + 255) & ~(size_t)255;
        return r;
    };
    unsigned int* tmpe = (unsigned int*)carve((size_t)NB * CAP * 4);  // bucketed edges -> CSR esrc (in place)
    int* bcur = (int*)carve((size_t)NB * 4);
    int* rs   = (int*)carve((size_t)N * 4);
    int* cnt  = (int*)carve((size_t)N * 4);
    float* msg = (float*)carve((size_t)N * DIM * 4);
    float* h1  = (float*)carve((size_t)N * DIM * 4);

    // ---- CSR build (bucketed two-pass; reused by both layers) ----
    k_zero_int<<<(NB + 255) / 256, 256, 0, stream>>>(bcur, NB);
    k_bucket<<<(E + 1023) / 1024, 256, 0, stream>>>(src, dst, bcur, tmpe, E);
    k_scatter<<<NB, 256, 0, stream>>>(tmpe, bcur, rs, cnt, N);

    // ---- layer 1 ----
    k_agg<<<(N + 3) / 4, 256, 0, stream>>>(x, rs, cnt, tmpe, msg, N);
    k_gemm<false><<<(N + 63) / 64, 256, 0, stream>>>(x, msg, Ws1, Wn1, b1, h1, N);

    // ---- layer 2 (norm fused into epilogue) ----
    k_agg<<<(N + 3) / 4, 256, 0, stream>>>(h1, rs, cnt, tmpe, msg, N);
    k_gemm<true><<<(N + 63) / 64, 256, 0, stream>>>(h1, msg, Ws2, Wn2, b2, out, N);
}

// Round 7
// 566.715 us; speedup vs baseline: 1.9191x; 1.9191x over previous
//
#include <hip/hip_runtime.h>
#include <math.h>

#define DIM 128
#define CAP 8192          // slots per bucket (mean fill 4096, sd ~64 -> never overflows)
#define BSHIFT 8          // 256 nodes per bucket
#define MAXNB 512         // max buckets supported (N <= 131072)

// ---------------------------------------------------------------- utilities
__global__ void k_zero_int(int* __restrict__ p, int n) {
    int i = blockIdx.x * blockDim.x + threadIdx.x;
    if (i < n) p[i] = 0;
}

// Pass A (block-batched): each block takes a chunk of edges, LDS-histograms
// the 391 buckets, reserves per-bucket space with ONE global atomic per
// (block,bucket) (~256 per address vs 4090/address in the per-edge version),
// then writes edges at base[b]+local_rank. Packed: src | (dst&255)<<17.
__global__ __launch_bounds__(256) void k_bucket(const int* __restrict__ src,
                                                const int* __restrict__ dst,
                                                int* __restrict__ bcur,
                                                unsigned int* __restrict__ tmpe,
                                                int E, int NB, int chunk) {
    __shared__ int hist[MAXNB];
    __shared__ int cur[MAXNB];
    int t = threadIdx.x;
    int begE = blockIdx.x * chunk;
    int endE = begE + chunk;
    if (endE > E) endE = E;

    hist[t] = 0;
    hist[t + 256] = 0;
    __syncthreads();

    for (int e = begE + t; e < endE; e += 256) {
        atomicAdd(&hist[dst[e] >> BSHIFT], 1);
    }
    __syncthreads();

    // one reservation atomic per (block,bucket); cur[b] becomes this block's
    // running slot index within bucket b's region
    if (t < NB)       cur[t]       = atomicAdd(&bcur[t], hist[t]);
    int t2 = t + 256;
    if (t2 < NB)      cur[t2]      = atomicAdd(&bcur[t2], hist[t2]);
    __syncthreads();

    for (int e = begE + t; e < endE; e += 256) {
        int s = src[e];
        int d = dst[e];
        int b = d >> BSHIFT;
        int p = atomicAdd(&cur[b], 1);   // LDS atomic
        if (p < CAP) tmpe[(size_t)b * CAP + p] = (unsigned int)s | ((unsigned int)(d & 255) << 17);
    }
}

// Pass B: one workgroup per bucket. Stage bucket edges in LDS, LDS-histogram
// the 256 local nodes (-> cnt), LDS-scan (-> rs), then scatter src ids back
// into the SAME global region grouped by node. Scatter target is one 16-32KB
// region => L2-hot, dense lines on eviction.
__global__ __launch_bounds__(256) void k_scatter(unsigned int* __restrict__ tmpe,
                                                 const int* __restrict__ bcur,
                                                 int* __restrict__ rs,
                                                 int* __restrict__ cnt,
                                                 int N) {
    __shared__ unsigned int se[CAP];   // 32 KB
    __shared__ int hist[256];
    __shared__ int sh[256];
    __shared__ int cur[256];
    int b = blockIdx.x;
    int t = threadIdx.x;
    size_t base = (size_t)b * CAP;
    int m = bcur[b];
    if (m > CAP) m = CAP;
    for (int i = t; i < m; i += 256) se[i] = tmpe[base + i];
    hist[t] = 0;
    __syncthreads();
    for (int i = t; i < m; i += 256) atomicAdd(&hist[se[i] >> 17], 1);
    __syncthreads();
    // exclusive scan of hist over 256 entries
    int v = hist[t];
    sh[t] = v;
    __syncthreads();
    int run = v;
    for (int off = 1; off < 256; off <<= 1) {
        int y = (t >= off) ? sh[t - off] : 0;
        __syncthreads();
        run += y;
        sh[t] = run;
        __syncthreads();
    }
    int excl = run - v;
    int node = (b << BSHIFT) + t;
    if (node < N) {
        rs[node] = (int)base + excl;
        cnt[node] = v;
    }
    cur[t] = excl;
    __syncthreads();
    // scatter: group src ids by local node, in place over the bucket region
    for (int i = t; i < m; i += 256) {
        unsigned int pk = se[i];
        int d = pk >> 17;
        int p = atomicAdd(&cur[d], 1);
        tmpe[base + p] = pk & 0x1FFFFu;
    }
}

// mean-aggregate: one wave per dst node. Each HALF-wave (32 lanes x float4 =
// 512B) covers a full 128-col row; halves take alternating edges; manual
// unroll-2 per half => 4 independent row-loads in flight per wave.
__global__ __launch_bounds__(256) void k_agg(const float* __restrict__ in,
                                             const int* __restrict__ rs,
                                             const int* __restrict__ cnt,
                                             const unsigned int* __restrict__ esrc,
                                             float* __restrict__ msg, int N) {
    int w = threadIdx.x >> 6;            // wave within block
    int half = (threadIdx.x >> 5) & 1;   // half-wave id
    int l32 = threadIdx.x & 31;          // lane within half
    int node = blockIdx.x * 4 + w;
    if (node >= N) return;
    int beg = rs[node];
    int deg = cnt[node];
    int end = beg + deg;
    int c = l32 * 4;
    float ax = 0.f, ay = 0.f, az = 0.f, aw = 0.f;
    int e = beg + half;                  // this half's first edge (stride 2)
    for (; e + 2 < end; e += 4) {        // unroll 2: edges e and e+2
        int s0 = esrc[e];
        int s1 = esrc[e + 2];
        float4 u = *(const float4*)(in + (size_t)s0 * DIM + c);
        float4 v = *(const float4*)(in + (size_t)s1 * DIM + c);
        ax += u.x + v.x;
        ay += u.y + v.y;
        az += u.z + v.z;
        aw += u.w + v.w;
    }
    if (e < end) {                       // at most one leftover per half
        int s0 = esrc[e];
        float4 u = *(const float4*)(in + (size_t)s0 * DIM + c);
        ax += u.x;
        ay += u.y;
        az += u.z;
        aw += u.w;
    }
    ax += __shfl_xor(ax, 32);
    ay += __shfl_xor(ay, 32);
    az += __shfl_xor(az, 32);
    aw += __shfl_xor(aw, 32);
    if (half == 0) {
        float invd = 1.0f / fmaxf((float)deg, 1.0f);
        float4 o;
        o.x = ax * invd;
        o.y = ay * invd;
        o.z = az * invd;
        o.w = aw * invd;
        *(float4*)(msg + (size_t)node * DIM + c) = o;
    }
}

// fused dual GEMM: out[m] = A[m] @ Ws^T + Hn[m] @ Wn^T + bias
// block: 256 threads, tile 64 rows x 128 cols (FULL rows), K chunks of 32.
// FUSE_NORM: L2-normalize rows in the epilogue (row spans 32 contiguous lanes).
template <bool FUSE_NORM>
__global__ __launch_bounds__(256) void k_gemm(const float* __restrict__ A,
                                              const float* __restrict__ Hn,
                                              const float* __restrict__ Ws,
                                              const float* __restrict__ Wn,
                                              const float* __restrict__ bias,
                                              float* __restrict__ out, int N) {
    __shared__ float As[32][68];   // k-major, padded
    __shared__ float Bs[32][132];  // k-major, padded
    int tid = threadIdx.x;
    int tr = tid >> 5;  // 0..7  -> row group (8 rows each)
    int tc = tid & 31;  // 0..31 -> col group (4 cols each)
    int m0 = blockIdx.x * 64;

    float acc[8][4];
#pragma unroll
    for (int i = 0; i < 8; ++i)
#pragma unroll
        for (int j = 0; j < 4; ++j) acc[i][j] = 0.f;

    for (int kb = 0; kb < 256; kb += 32) {
        const float* srcA = (kb < 128) ? A : Hn;
        const float* srcB = (kb < 128) ? Ws : Wn;
        int ka = kb & 127;
#pragma unroll
        for (int i = 0; i < 2; ++i) {
            int fi = tid + i * 256;
            int row = fi >> 3, kq = fi & 7;
            int m = m0 + row;
            float4 v = make_float4(0.f, 0.f, 0.f, 0.f);
            if (m < N) v = *(const float4*)(srcA + (size_t)m * DIM + ka + kq * 4);
            As[kq * 4 + 0][row] = v.x;
            As[kq * 4 + 1][row] = v.y;
            As[kq * 4 + 2][row] = v.z;
            As[kq * 4 + 3][row] = v.w;
        }
#pragma unroll
        for (int i = 0; i < 4; ++i) {
            int fi = tid + i * 256;
            int o = fi >> 3, kq = fi & 7;
            float4 v = *(const float4*)(srcB + o * DIM + ka + kq * 4);
            Bs[kq * 4 + 0][o] = v.x;
            Bs[kq * 4 + 1][o] = v.y;
            Bs[kq * 4 + 2][o] = v.z;
            Bs[kq * 4 + 3][o] = v.w;
        }
        __syncthreads();
#pragma unroll
        for (int kk = 0; kk < 32; ++kk) {
            float4 a0 = *(const float4*)&As[kk][tr * 8];
            float4 a1 = *(const float4*)&As[kk][tr * 8 + 4];
            float4 bv = *(const float4*)&Bs[kk][tc * 4];
            float av[8] = {a0.x, a0.y, a0.z, a0.w, a1.x, a1.y, a1.z, a1.w};
            float bw[4] = {bv.x, bv.y, bv.z, bv.w};
#pragma unroll
            for (int i = 0; i < 8; ++i)
#pragma unroll
                for (int j = 0; j < 4; ++j) acc[i][j] += av[i] * bw[j];
        }
        __syncthreads();
    }
    float4 bb = *(const float4*)(bias + tc * 4);
#pragma unroll
    for (int i = 0; i < 8; ++i) {
        int m = m0 + tr * 8 + i;
        if (m < N) {
            float4 o;
            o.x = acc[i][0] + bb.x;
            o.y = acc[i][1] + bb.y;
            o.z = acc[i][2] + bb.z;
            o.w = acc[i][3] + bb.w;
            if (FUSE_NORM) {
                float ss = o.x * o.x + o.y * o.y + o.z * o.z + o.w * o.w;
                ss += __shfl_xor(ss, 16);
                ss += __shfl_xor(ss, 8);
                ss += __shfl_xor(ss, 4);
                ss += __shfl_xor(ss, 2);
                ss += __shfl_xor(ss, 1);
                float scale = 1.0f / fmaxf(sqrtf(ss), 1e-12f);
                o.x *= scale;
                o.y *= scale;
                o.z *= scale;
                o.w *= scale;
            }
            *(float4*)(out + (size_t)m * DIM + tc * 4) = o;
        }
    }
}

extern "C" void kernel_launch(void* const* d_in, const int* in_sizes, int n_in,
                              void* d_out, int out_size, void* d_ws, size_t ws_size,
                              hipStream_t stream) {
    const float* x   = (const float*)d_in[0];
    const int*   src = (const int*)d_in[1];
    const int*   dst = (const int*)d_in[2];
    const float* Ws1 = (const float*)d_in[3];
    const float* Wn1 = (const float*)d_in[4];
    const float* b1  = (const float*)d_in[5];
    const float* Ws2 = (const float*)d_in[6];
    const float* Wn2 = (const float*)d_in[7];
    const float* b2  = (const float*)d_in[8];
    float* out = (float*)d_out;

    int N = in_sizes[0] / DIM;
    int E = in_sizes[1];
    int NB = (N + (1 << BSHIFT) - 1) >> BSHIFT;

    // workspace carve-up (256B aligned)
    char* p = (char*)d_ws;
    size_t off = 0;
    auto carve = [&](size_t bytes) {
        void* r = p + off;
        off = (off + bytes + 255) & ~(size_t)255;
        return r;
    };
    unsigned int* tmpe = (unsigned int*)carve((size_t)NB * CAP * 4);  // bucketed edges -> CSR esrc (in place)
    int* bcur = (int*)carve((size_t)NB * 4);
    int* rs   = (int*)carve((size_t)N * 4);
    int* cnt  = (int*)carve((size_t)N * 4);
    float* msg = (float*)carve((size_t)N * DIM * 4);
    float* h1  = (float*)carve((size_t)N * DIM * 4);

    // ---- CSR build (bucketed two-pass, block-batched reservations) ----
    int grid_b = 256;
    int chunk = (E + grid_b - 1) / grid_b;
    k_zero_int<<<(NB + 255) / 256, 256, 0, stream>>>(bcur, NB);
    k_bucket<<<grid_b, 256, 0, stream>>>(src, dst, bcur, tmpe, E, NB, chunk);
    k_scatter<<<NB, 256, 0, stream>>>(tmpe, bcur, rs, cnt, N);

    // ---- layer 1 ----
    k_agg<<<(N + 3) / 4, 256, 0, stream>>>(x, rs, cnt, tmpe, msg, N);
    k_gemm<false><<<(N + 63) / 64, 256, 0, stream>>>(x, msg, Ws1, Wn1, b1, h1, N);

    // ---- layer 2 (norm fused into epilogue) ----
    k_agg<<<(N + 3) / 4, 256, 0, stream>>>(h1, rs, cnt, tmpe, msg, N);
    k_gemm<true><<<(N + 63) / 64, 256, 0, stream>>>(h1, msg, Ws2, Wn2, b2, out, N);
}